// Round 11
// baseline (2035.585 us; speedup 1.0000x reference)
//
#include <hip/hip_runtime.h>
#include <hip/hip_bf16.h>

// EntityTable: B=16,T=2048,D=1024,N_E=8,D_E=64
// Phase A (parallel): hp = h@Wi^T + bi ; logits = h@ek^T/32 ; w = softmax(logits)
//                     P  = W_ih @ hp   (entity-independent input-gate projection)
// Phase B (sequential scan over T): per cell (b,n):
//   gx_k = w*P_k + b_ih_k ; gh_k = W_hh[k]·s + b_hh_k
//   r=sig(gx0+gh0) z=sig(gx1+gh1) n=tanh(gx2 + r*gh2) ; s' = (1-z)n + z s
//
// Round-11 scan: TWO CELLS PER WAVE, fp32. All cells share W_hh, so one set
// of weight registers (and any AGPR-unpark moves - the RA caps this kernel at
// ~132 arch VGPRs, proven r4-r10) serves two MAC streams: residency tax
// halves per cell, and each cell's LDS state-hop + transcendental latency
// hides under the other cell's pk_fma issue. Cells (b,2u),(b,2u+1) share the
// same P rows (entity-independent) -> single P load stream. r5 flavor
// otherwise: named SSA weights, no keep-alive, no waves_per_eu attr.

constexpr int B_  = 16;
constexpr int T_  = 2048;
constexpr int D_  = 1024;
constexpr int NE  = 8;
constexpr int DE  = 64;
constexpr int G3  = 192;            // 3*DE
constexpr int ROWS = B_ * T_;       // 32768
constexpr int OUT1OFF = ROWS * NE * DE;  // 16777216

typedef __attribute__((ext_vector_type(2))) float f32x2;
typedef __attribute__((ext_vector_type(4))) float f32x4;

__device__ __forceinline__ void pkacc(f32x2& acc, f32x2 w, f32x2 s) {
    asm("v_pk_fma_f32 %0, %1, %2, %0" : "+v"(acc) : "v"(w), "v"(s));
}

// ---------------- Kernel T: transpose Wi -> WT4 ----------------
__global__ __launch_bounds__(256) void wt_kernel(
    const float* __restrict__ Wi, float* __restrict__ WT4)
{
    const int o  = blockIdx.x;     // 64 blocks
    const int dq = threadIdx.x;    // 256 threads
    const float4 v = *(const float4*)&Wi[o * D_ + dq * 4];
    *(float4*)&WT4[(dq * 64 + o) * 4] = v;
}

// ---------------- Kernel A: projection + routing + P ----------------
constexpr int RPB = 32;   // rows per block
constexpr int CH  = 128;  // K-chunk

__global__ __launch_bounds__(256) void proj_kernel(
    const float* __restrict__ h,   const float* __restrict__ ek,
    const float* __restrict__ WT4, const float* __restrict__ bi,
    const float* __restrict__ Wih,
    float* __restrict__ Pout, float* __restrict__ wout)
{
    __shared__ float hch[RPB][CH];   // 16 KB
    __shared__ float hp[RPB][DE];    // 8 KB
    __shared__ float lg[RPB][NE];    // 1 KB

    const int tid = threadIdx.x;
    const int brow = blockIdx.x * RPB;
    const int w = tid >> 6;          // wave 0..3
    const int o = tid & 63;          // lane = output index for hp
    const int n  = o & 7;            // entity for logit partial
    const int sl = o >> 3;           // K-slice for logit partial

    float acc[8], accl[8];
#pragma unroll
    for (int r = 0; r < 8; ++r) { acc[r] = 0.f; accl[r] = 0.f; }

    for (int kc = 0; kc < D_; kc += CH) {
        __syncthreads();
#pragma unroll
        for (int i = 0; i < 4; ++i) {
            int idx = tid + i * 256;
            int lr = idx >> 5;
            int c4 = (idx & 31) * 4;
            *(float4*)&hch[lr][c4] =
                *(const float4*)&h[(size_t)(brow + lr) * D_ + kc + c4];
        }
        __syncthreads();

        for (int d4 = 0; d4 < CH / 4; ++d4) {
            const float4 wt = *(const float4*)&WT4[((kc >> 2) + d4) * 256 + (o << 2)];
#pragma unroll
            for (int r = 0; r < 8; ++r) {
                const float4 h4 = *(const float4*)&hch[w * 8 + r][d4 * 4];
                acc[r] = fmaf(wt.x, h4.x,
                         fmaf(wt.y, h4.y,
                         fmaf(wt.z, h4.z,
                         fmaf(wt.w, h4.w, acc[r]))));
            }
        }
#pragma unroll
        for (int i4 = 0; i4 < 4; ++i4) {
            const int dl = sl * 16 + i4 * 4;
            const float4 e4 = *(const float4*)&ek[n * D_ + kc + dl];
#pragma unroll
            for (int r = 0; r < 8; ++r) {
                const float4 h4 = *(const float4*)&hch[w * 8 + r][dl];
                accl[r] = fmaf(e4.x, h4.x,
                          fmaf(e4.y, h4.y,
                          fmaf(e4.z, h4.z,
                          fmaf(e4.w, h4.w, accl[r]))));
            }
        }
    }

    const float biv = bi[o];
#pragma unroll
    for (int r = 0; r < 8; ++r) hp[w * 8 + r][o] = acc[r] + biv;

#pragma unroll
    for (int r = 0; r < 8; ++r) {
        accl[r] += __shfl_xor(accl[r], 8);
        accl[r] += __shfl_xor(accl[r], 16);
        accl[r] += __shfl_xor(accl[r], 32);
    }
    if (sl == 0) {
#pragma unroll
        for (int r = 0; r < 8; ++r) lg[w * 8 + r][n] = accl[r] * 0.03125f;
    }
    __syncthreads();

    if (tid < RPB) {
        const int lr = tid;
        float v[NE];
        float m = -1e30f;
#pragma unroll
        for (int e = 0; e < NE; ++e) { v[e] = lg[lr][e]; m = fmaxf(m, v[e]); }
        float s = 0.f;
#pragma unroll
        for (int e = 0; e < NE; ++e) { v[e] = __expf(v[e] - m); s += v[e]; }
        const float inv = 1.f / s;
#pragma unroll
        for (int e = 0; e < NE; ++e)
            wout[(size_t)(brow + lr) * NE + e] = v[e] * inv;
    }

    if (tid < G3) {
        const int k = tid;
        for (int lr0 = 0; lr0 < RPB; lr0 += 8) {
            float pacc[8];
#pragma unroll
            for (int r = 0; r < 8; ++r) pacc[r] = 0.f;
            for (int d4 = 0; d4 < DE / 4; ++d4) {
                const float4 wv = *(const float4*)&Wih[k * DE + d4 * 4];
#pragma unroll
                for (int r = 0; r < 8; ++r) {
                    const float4 h4 = *(const float4*)&hp[lr0 + r][d4 * 4];
                    pacc[r] = fmaf(wv.x, h4.x,
                              fmaf(wv.y, h4.y,
                              fmaf(wv.z, h4.z,
                              fmaf(wv.w, h4.w, pacc[r]))));
                }
            }
#pragma unroll
            for (int r = 0; r < 8; ++r)
                Pout[(size_t)(brow + lr0 + r) * G3 + k] = pacc[r];
        }
    }
}

// ---------------- Kernel B: two-cell-per-wave fp32 GRU scan ----------------
#define DW(pre, base, q) \
    f32x4 pre##q = *(const f32x4*)&Whh[(size_t)(base + j) * 64 + 4 * (q)];
#define DW16(pre, base) \
    DW(pre, base, 0)  DW(pre, base, 1)  DW(pre, base, 2)  DW(pre, base, 3)  \
    DW(pre, base, 4)  DW(pre, base, 5)  DW(pre, base, 6)  DW(pre, base, 7)  \
    DW(pre, base, 8)  DW(pre, base, 9)  DW(pre, base, 10) DW(pre, base, 11) \
    DW(pre, base, 12) DW(pre, base, 13) DW(pre, base, 14) DW(pre, base, 15)

// fused MAC over both cells: 12 pk_fma per q, 6 independent chains
#define MACQ(q) { \
    const f32x4 a4 = *(const f32x4*)&sA[4 * (q)]; \
    const f32x4 b4 = *(const f32x4*)&sB[4 * (q)]; \
    pkacc(aRA, wr##q.lo, a4.lo); pkacc(aZA, wz##q.lo, a4.lo); \
    pkacc(aNA, wn##q.lo, a4.lo); \
    pkacc(aRB, wr##q.lo, b4.lo); pkacc(aZB, wz##q.lo, b4.lo); \
    pkacc(aNB, wn##q.lo, b4.lo); \
    pkacc(aRA, wr##q.hi, a4.hi); pkacc(aZA, wz##q.hi, a4.hi); \
    pkacc(aNA, wn##q.hi, a4.hi); \
    pkacc(aRB, wr##q.hi, b4.hi); pkacc(aZB, wz##q.hi, b4.hi); \
    pkacc(aNB, wn##q.hi, b4.hi); }
#define MAC16() \
    MACQ(0)  MACQ(1)  MACQ(2)  MACQ(3)  MACQ(4)  MACQ(5)  MACQ(6)  MACQ(7) \
    MACQ(8)  MACQ(9)  MACQ(10) MACQ(11) MACQ(12) MACQ(13) MACQ(14) MACQ(15)

__global__ __launch_bounds__(64, 1) void scan_kernel(
    const float* __restrict__ P,   const float* __restrict__ route,
    const float* __restrict__ Whh, const float* __restrict__ bih,
    const float* __restrict__ bhh, const float* __restrict__ e0,
    float* __restrict__ out, int write1)
{
    __shared__ __align__(16) float sA[DE];
    __shared__ __align__(16) float sB[DE];

    // 64 blocks; batch b's 4 blocks (u=0..3) co-located on XCD b>>1
    const int g   = blockIdx.x;
    const int xcd = g & 7;
    const int ii  = g >> 3;              // 0..7
    const int b   = (xcd << 1) | (ii & 1);
    const int u   = ii >> 1;             // 0..3
    const int nA  = 2 * u;
    const int nB  = nA + 1;
    const int j   = threadIdx.x;         // 0..63

    // 48 named SSA f32x4 weights, shared by both cells
    DW16(wr, 0)
    DW16(wz, 64)
    DW16(wn, 128)

    const float Br   = bih[j] + bhh[j];            // combined r bias
    const float Bz   = bih[64 + j] + bhh[64 + j];  // combined z bias
    const float bin_ = bih[128 + j];
    const float bhn_ = bhh[128 + j];

    const size_t row0 = (size_t)b * T_;
    float sregA = e0[nA * DE + j];
    float sregB = e0[nB * DE + j];
    sA[j] = sregA;                       // same-wave ds ordering, no barrier
    sB[j] = sregB;

    const float* Pb = P + row0 * G3;
    const float* rb = route + row0 * NE;
    float* opA = out + row0 * (size_t)(NE * DE) + nA * DE + j;
    float* opB = out + row0 * (size_t)(NE * DE) + nB * DE + j;

    // software prefetch, depth = 2 steps (P shared; route per cell)
    float pr0 = Pb[j],       pr1 = Pb[G3 + j];
    float pz0 = Pb[64 + j],  pz1 = Pb[G3 + 64 + j];
    float pn0 = Pb[128 + j], pn1 = Pb[G3 + 128 + j];
    float wA0 = rb[nA],      wA1 = rb[NE + nA];
    float wB0 = rb[nB],      wB1 = rb[NE + nB];

    for (int t0 = 0; t0 < T_; t0 += 2) {
        const int tb = (t0 + 2 < T_) ? (t0 + 2) : t0;   // tail clamp (harmless)
        const float qr0 = Pb[(size_t)(tb) * G3 + j];
        const float qz0 = Pb[(size_t)(tb) * G3 + 64 + j];
        const float qn0 = Pb[(size_t)(tb) * G3 + 128 + j];
        const float qA0 = rb[(size_t)tb * NE + nA];
        const float qB0 = rb[(size_t)tb * NE + nB];
        const float qr1 = Pb[(size_t)(tb + 1) * G3 + j];
        const float qz1 = Pb[(size_t)(tb + 1) * G3 + 64 + j];
        const float qn1 = Pb[(size_t)(tb + 1) * G3 + 128 + j];
        const float qA1 = rb[(size_t)(tb + 1) * NE + nA];
        const float qB1 = rb[(size_t)(tb + 1) * NE + nB];

#pragma unroll
        for (int i = 0; i < 2; ++i) {
            const float pri = i ? pr1 : pr0;
            const float pzi = i ? pz1 : pz0;
            const float pni = i ? pn1 : pn0;
            const float wAi = i ? wA1 : wA0;
            const float wBi = i ? wB1 : wB0;

            f32x2 aRA = {0.f, 0.f}, aZA = {0.f, 0.f}, aNA = {0.f, 0.f};
            f32x2 aRB = {0.f, 0.f}, aZB = {0.f, 0.f}, aNB = {0.f, 0.f};
            MAC16()

            // ---- cell A activation ----
            const float argRA = (aRA.x + aRA.y) + fmaf(wAi, pri, Br);
            const float argZA = (aZA.x + aZA.y) + fmaf(wAi, pzi, Bz);
            const float rrA = __builtin_amdgcn_rcpf(1.f + __expf(-argRA));
            const float zzA = __builtin_amdgcn_rcpf(1.f + __expf(-argZA));
            const float uA  = fmaf(wAi, pni, bin_);
            const float vA  = (aNA.x + aNA.y) + bhn_;
            const float xA  = fmaf(rrA, vA, uA);
            const float nnA = fmaf(2.f, __builtin_amdgcn_rcpf(1.f + __expf(-2.f * xA)), -1.f);
            const float snA = fmaf(zzA, sregA - nnA, nnA);   // (1-z)n + z s
            // ---- cell B activation (independent; scheduler interleaves) ----
            const float argRB = (aRB.x + aRB.y) + fmaf(wBi, pri, Br);
            const float argZB = (aZB.x + aZB.y) + fmaf(wBi, pzi, Bz);
            const float rrB = __builtin_amdgcn_rcpf(1.f + __expf(-argRB));
            const float zzB = __builtin_amdgcn_rcpf(1.f + __expf(-argZB));
            const float uB  = fmaf(wBi, pni, bin_);
            const float vB  = (aNB.x + aNB.y) + bhn_;
            const float xB  = fmaf(rrB, vB, uB);
            const float nnB = fmaf(2.f, __builtin_amdgcn_rcpf(1.f + __expf(-2.f * xB)), -1.f);
            const float snB = fmaf(zzB, sregB - nnB, nnB);

            sregA = snA; sA[j] = snA;
            sregB = snB; sB[j] = snB;

            const size_t toff = (size_t)(t0 + i) * (NE * DE);
            opA[toff] = snA;
            opB[toff] = snB;
            if (write1) { opA[OUT1OFF + toff] = snA; opB[OUT1OFF + toff] = snB; }
        }

        pr0 = qr0; pz0 = qz0; pn0 = qn0; wA0 = qA0; wB0 = qB0;
        pr1 = qr1; pz1 = qz1; pn1 = qn1; wA1 = qA1; wB1 = qB1;
    }
}

// ---------------- Kernel C: replicate out0 -> out1 (stash path) ----------------
__global__ __launch_bounds__(256) void copy_kernel(
    const float4* __restrict__ src, float4* __restrict__ dst, int n4)
{
    int i = blockIdx.x * 256 + threadIdx.x;
    const int stride = gridDim.x * 256;
    for (; i < n4; i += stride) dst[i] = src[i];
}

extern "C" void kernel_launch(void* const* d_in, const int* in_sizes, int n_in,
                              void* d_out, int out_size, void* d_ws, size_t ws_size,
                              hipStream_t stream) {
    const float* h_seq = (const float*)d_in[0];
    const float* ek    = (const float*)d_in[1];
    const float* Wi    = (const float*)d_in[2];
    const float* bi    = (const float*)d_in[3];
    const float* Wih   = (const float*)d_in[4];
    const float* Whh   = (const float*)d_in[5];
    const float* bih   = (const float*)d_in[6];
    const float* bhh   = (const float*)d_in[7];
    const float* e0    = (const float*)d_in[8];
    float* out = (float*)d_out;

    const size_t need = (size_t)ROWS * (G3 + NE) * sizeof(float)
                      + (size_t)DE * D_ * sizeof(float);  // ~26.5 MB
    float* wbuf;
    int write1;
    if (ws_size >= need) {
        wbuf = (float*)d_ws;
        write1 = 1;                    // scan writes both output copies
    } else {
        wbuf = out + OUT1OFF;          // stash in out1; copy at the end
        write1 = 0;
    }
    float* Pbuf = wbuf + (size_t)ROWS * NE;
    float* WT4  = Pbuf + (size_t)ROWS * G3;

    wt_kernel<<<DE, 256, 0, stream>>>(Wi, WT4);
    proj_kernel<<<ROWS / RPB, 256, 0, stream>>>(h_seq, ek, WT4, bi, Wih, Pbuf, wbuf);
    scan_kernel<<<B_ * NE / 2, 64, 0, stream>>>(Pbuf, wbuf, Whh, bih, bhh, e0, out, write1);

    if (!write1) {
        copy_kernel<<<2048, 256, 0, stream>>>((const float4*)out,
                                              (float4*)(out + OUT1OFF), OUT1OFF / 4);
    }
}

// Round 13
// 1181.562 us; speedup vs baseline: 1.7228x; 1.7228x over previous
//
#include <hip/hip_runtime.h>
#include <hip/hip_bf16.h>

// EntityTable: B=16,T=2048,D=1024,N_E=8,D_E=64
// Phase A (parallel): hp = h@Wi^T + bi ; logits = h@ek^T/32 ; w = softmax(logits)
//                     P  = W_ih @ hp   (entity-independent input-gate projection)
// Phase B (sequential scan over T): per cell (b,n):
//   gx_k = w*P_k + b_ih_k ; gh_k = W_hh[k]·s + b_hh_k
//   r=sig(gx0+gh0) z=sig(gx1+gh1) n=tanh(gx2 + r*gh2) ; s' = (1-z)n + z s
//
// Round-13: scan = r5-exact (842us, best of 8 variants; single wave, 1 LDS
// hop, 0 barriers). NEW proj: lane-per-row with h in registers and Wi at
// WAVE-UNIFORM addresses -> s_load to SGPRs (scalar pipe) + v_fma with SGPR
// operand. Kills the DS-bound inner loop (old: 1 ds_read_b128 per 4 FMA,
// ~180us of DS serialization). Cross-wave k-quarter reduce via ds_add_f32.

constexpr int B_  = 16;
constexpr int T_  = 2048;
constexpr int D_  = 1024;
constexpr int NE  = 8;
constexpr int DE  = 64;
constexpr int G3  = 192;            // 3*DE
constexpr int ROWS = B_ * T_;       // 32768
constexpr int OUT1OFF = ROWS * NE * DE;  // 16777216

typedef __attribute__((ext_vector_type(2))) float f32x2;
typedef __attribute__((ext_vector_type(4))) float f32x4;

__device__ __forceinline__ void pkacc(f32x2& acc, f32x2 w, f32x2 s) {
    asm("v_pk_fma_f32 %0, %1, %2, %0" : "+v"(acc) : "v"(w), "v"(s));
}

// ---------------- Kernel A: projection + routing + P (SGPR-weight design) ----------------
// 512 blocks x 256 thr. 64 rows/block; wave w owns k-quarter [256w,256w+256).
// Lane r = row. h sub-chunk (64 floats) in registers; Wi/ek rows are
// wave-uniform -> scalar loads; accumulate into LDS hp_l[o][r] via ds_add_f32.
constexpr int PRJ_ROWS = 64;

__global__ __launch_bounds__(256) void proj_kernel(
    const float* __restrict__ h,   const float* __restrict__ ek,
    const float* __restrict__ Wi,  const float* __restrict__ bi,
    const float* __restrict__ Wih,
    float* __restrict__ Pout, float* __restrict__ wout)
{
    __shared__ float hp_l[72][PRJ_ROWS];   // [64 hp + 8 logit][row], 18.4 KB

    const int tid  = threadIdx.x;
    const int w    = tid >> 6;             // wave = k-quarter index
    const int r    = tid & 63;             // row within block
    const int brow = blockIdx.x * PRJ_ROWS;

    // zero the accumulator array
    for (int i = tid; i < 72 * PRJ_ROWS; i += 256) ((float*)hp_l)[i] = 0.f;
    __syncthreads();

    const float* hrow = h + (size_t)(brow + r) * D_ + w * 256;

    for (int kc = 0; kc < 4; ++kc) {       // 4 sub-chunks of 64 k
        // this lane's 64 h values -> 16 float4 registers
        float4 hs[16];
#pragma unroll
        for (int i = 0; i < 16; ++i)
            hs[i] = *(const float4*)&hrow[kc * 64 + i * 4];

        // 72 outputs: o<64 -> Wi row o ; o>=64 -> entity key row o-64
        for (int o = 0; o < 72; ++o) {
            const float* wrow = (o < 64)
                ? (Wi  + (size_t)o * D_        + w * 256 + kc * 64)
                : (ek  + (size_t)(o - 64) * D_ + w * 256 + kc * 64);
            float a0 = 0.f, a1 = 0.f, a2 = 0.f, a3 = 0.f;
#pragma unroll
            for (int i = 0; i < 16; i += 4) {
                const float4 w0 = *(const float4*)&wrow[(i + 0) * 4];
                const float4 w1 = *(const float4*)&wrow[(i + 1) * 4];
                const float4 w2 = *(const float4*)&wrow[(i + 2) * 4];
                const float4 w3 = *(const float4*)&wrow[(i + 3) * 4];
                a0 = fmaf(w0.x, hs[i+0].x, fmaf(w0.y, hs[i+0].y,
                     fmaf(w0.z, hs[i+0].z, fmaf(w0.w, hs[i+0].w, a0))));
                a1 = fmaf(w1.x, hs[i+1].x, fmaf(w1.y, hs[i+1].y,
                     fmaf(w1.z, hs[i+1].z, fmaf(w1.w, hs[i+1].w, a1))));
                a2 = fmaf(w2.x, hs[i+2].x, fmaf(w2.y, hs[i+2].y,
                     fmaf(w2.z, hs[i+2].z, fmaf(w2.w, hs[i+2].w, a2))));
                a3 = fmaf(w3.x, hs[i+3].x, fmaf(w3.y, hs[i+3].y,
                     fmaf(w3.z, hs[i+3].z, fmaf(w3.w, hs[i+3].w, a3))));
            }
            atomicAdd(&hp_l[o][r], (a0 + a1) + (a2 + a3));
        }
    }
    __syncthreads();

    // ---- softmax over the 8 logits (wave 0, lane = row) ----
    if (tid < PRJ_ROWS) {
        float v[NE];
        float m = -1e30f;
#pragma unroll
        for (int e = 0; e < NE; ++e) {
            v[e] = hp_l[64 + e][tid] * 0.03125f;
            m = fmaxf(m, v[e]);
        }
        float s = 0.f;
#pragma unroll
        for (int e = 0; e < NE; ++e) { v[e] = __expf(v[e] - m); s += v[e]; }
        const float inv = 1.f / s;
#pragma unroll
        for (int e = 0; e < NE; ++e)
            wout[(size_t)(brow + tid) * NE + e] = v[e] * inv;
    }

    // ---- P = W_ih @ (hp + bi) : wave w handles outputs [48w, 48w+48) ----
    // lane r's hp row into registers (conflict-free: lanes consecutive)
    float hpr[DE];
#pragma unroll
    for (int k = 0; k < DE; ++k)
        hpr[k] = hp_l[k][r] + bi[k];        // bi[k] wave-uniform scalar load

    float* prow = Pout + (size_t)(brow + r) * G3;
    for (int o2 = 48 * w; o2 < 48 * w + 48; ++o2) {
        const float* wr2 = Wih + (size_t)o2 * DE;   // wave-uniform row
        float a0 = 0.f, a1 = 0.f, a2 = 0.f, a3 = 0.f;
#pragma unroll
        for (int i = 0; i < 16; i += 4) {
            const float4 w0 = *(const float4*)&wr2[(i + 0) * 4];
            const float4 w1 = *(const float4*)&wr2[(i + 1) * 4];
            const float4 w2 = *(const float4*)&wr2[(i + 2) * 4];
            const float4 w3 = *(const float4*)&wr2[(i + 3) * 4];
            a0 = fmaf(w0.x, hpr[(i+0)*4+0], fmaf(w0.y, hpr[(i+0)*4+1],
                 fmaf(w0.z, hpr[(i+0)*4+2], fmaf(w0.w, hpr[(i+0)*4+3], a0))));
            a1 = fmaf(w1.x, hpr[(i+1)*4+0], fmaf(w1.y, hpr[(i+1)*4+1],
                 fmaf(w1.z, hpr[(i+1)*4+2], fmaf(w1.w, hpr[(i+1)*4+3], a1))));
            a2 = fmaf(w2.x, hpr[(i+2)*4+0], fmaf(w2.y, hpr[(i+2)*4+1],
                 fmaf(w2.z, hpr[(i+2)*4+2], fmaf(w2.w, hpr[(i+2)*4+3], a2))));
            a3 = fmaf(w3.x, hpr[(i+3)*4+0], fmaf(w3.y, hpr[(i+3)*4+1],
                 fmaf(w3.z, hpr[(i+3)*4+2], fmaf(w3.w, hpr[(i+3)*4+3], a3))));
        }
        prow[o2] = (a0 + a1) + (a2 + a3);
    }
}

// ---------------- Kernel B: one-wave-per-cell GRU scan (r5-exact) ----------------
#define DW(pre, base, q) \
    const f32x4 pre##q = *(const f32x4*)&Whh[(size_t)(base + j) * 64 + 4 * (q)];
#define DW16(pre, base) \
    DW(pre, base, 0)  DW(pre, base, 1)  DW(pre, base, 2)  DW(pre, base, 3)  \
    DW(pre, base, 4)  DW(pre, base, 5)  DW(pre, base, 6)  DW(pre, base, 7)  \
    DW(pre, base, 8)  DW(pre, base, 9)  DW(pre, base, 10) DW(pre, base, 11) \
    DW(pre, base, 12) DW(pre, base, 13) DW(pre, base, 14) DW(pre, base, 15)

#define MACQ(q) { \
    const f32x4 s4 = *(const f32x4*)&s_l[4 * (q)]; \
    const f32x2 lo = s4.lo, hi = s4.hi; \
    pkacc(aR, wr##q.lo, lo); pkacc(aR, wr##q.hi, hi); \
    pkacc(aZ, wz##q.lo, lo); pkacc(aZ, wz##q.hi, hi); \
    pkacc(aN, wn##q.lo, lo); pkacc(aN, wn##q.hi, hi); }
#define MAC16() \
    MACQ(0)  MACQ(1)  MACQ(2)  MACQ(3)  MACQ(4)  MACQ(5)  MACQ(6)  MACQ(7) \
    MACQ(8)  MACQ(9)  MACQ(10) MACQ(11) MACQ(12) MACQ(13) MACQ(14) MACQ(15)

__global__ __launch_bounds__(64, 1) void scan_kernel(
    const float* __restrict__ P,   const float* __restrict__ route,
    const float* __restrict__ Whh, const float* __restrict__ bih,
    const float* __restrict__ bhh, const float* __restrict__ e0,
    float* __restrict__ out)
{
    __shared__ __align__(16) float s_l[DE];

    // XCD co-location: entity-cells of a batch share the P rows in L2
    const int g   = blockIdx.x;          // 0..127
    const int xcd = g & 7;
    const int ii  = g >> 3;              // 0..15
    const int b   = xcd + 8 * (ii & 1);
    const int n   = ii >> 1;
    const int j   = threadIdx.x;         // 0..63

    DW16(wr, 0)
    DW16(wz, 64)
    DW16(wn, 128)

    const float Br   = bih[j] + bhh[j];            // combined r bias
    const float Bz   = bih[64 + j] + bhh[64 + j];  // combined z bias
    const float bin_ = bih[128 + j];
    const float bhn_ = bhh[128 + j];

    const size_t row0 = (size_t)b * T_;
    float s_reg = e0[n * DE + j];
    s_l[j] = s_reg;                      // same-wave ds ordering, no barrier

    const float* Pb = P + row0 * G3;
    const float* wb = route + row0 * NE + n;
    float* op = out + row0 * (size_t)(NE * DE) + n * DE + j;

    // software prefetch, depth = 2 steps
    float pr0 = Pb[j],            pr1 = Pb[G3 + j];
    float pz0 = Pb[64 + j],       pz1 = Pb[G3 + 64 + j];
    float pn0 = Pb[128 + j],      pn1 = Pb[G3 + 128 + j];
    float wv0 = wb[0],            wv1 = wb[NE];

    for (int t0 = 0; t0 < T_; t0 += 2) {
        const int tb = (t0 + 2 < T_) ? (t0 + 2) : t0;   // tail clamp (reload, harmless)
        const float qr0 = Pb[(size_t)(tb) * G3 + j];
        const float qz0 = Pb[(size_t)(tb) * G3 + 64 + j];
        const float qn0 = Pb[(size_t)(tb) * G3 + 128 + j];
        const float qw0 = wb[tb * NE];
        const float qr1 = Pb[(size_t)(tb + 1) * G3 + j];
        const float qz1 = Pb[(size_t)(tb + 1) * G3 + 64 + j];
        const float qn1 = Pb[(size_t)(tb + 1) * G3 + 128 + j];
        const float qw1 = wb[(tb + 1) * NE];

#pragma unroll
        for (int i = 0; i < 2; ++i) {
            const float pri = i ? pr1 : pr0;
            const float pzi = i ? pz1 : pz0;
            const float pni = i ? pn1 : pn0;
            const float wvi = i ? wv1 : wv0;

            f32x2 aR = {0.f, 0.f}, aZ = {0.f, 0.f}, aN = {0.f, 0.f};
            MAC16()

            const float argR = (aR.x + aR.y) + fmaf(wvi, pri, Br);
            const float argZ = (aZ.x + aZ.y) + fmaf(wvi, pzi, Bz);
            const float rr = __builtin_amdgcn_rcpf(1.f + __expf(-argR));
            const float zz = __builtin_amdgcn_rcpf(1.f + __expf(-argZ));
            const float u  = fmaf(wvi, pni, bin_);
            const float v  = (aN.x + aN.y) + bhn_;
            const float x  = fmaf(rr, v, u);
            const float nn = fmaf(2.f, __builtin_amdgcn_rcpf(1.f + __expf(-2.f * x)), -1.f);
            const float snew = fmaf(zz, s_reg - nn, nn);   // (1-z)n + z s
            s_reg = snew;
            s_l[j] = snew;               // the single cross-lane hop
            op[(size_t)(t0 + i) * (NE * DE)] = snew;
        }

        pr0 = qr0; pz0 = qz0; pn0 = qn0; wv0 = qw0;
        pr1 = qr1; pz1 = qz1; pn1 = qn1; wv1 = qw1;
    }
}

// ---------------- Kernel C: replicate out0 -> out1 ----------------
__global__ __launch_bounds__(256) void copy_kernel(
    const float4* __restrict__ src, float4* __restrict__ dst, int n4)
{
    int i = blockIdx.x * 256 + threadIdx.x;
    const int stride = gridDim.x * 256;
    for (; i < n4; i += stride) dst[i] = src[i];
}

extern "C" void kernel_launch(void* const* d_in, const int* in_sizes, int n_in,
                              void* d_out, int out_size, void* d_ws, size_t ws_size,
                              hipStream_t stream) {
    const float* h_seq = (const float*)d_in[0];
    const float* ek    = (const float*)d_in[1];
    const float* Wi    = (const float*)d_in[2];
    const float* bi    = (const float*)d_in[3];
    const float* Wih   = (const float*)d_in[4];
    const float* Whh   = (const float*)d_in[5];
    const float* bih   = (const float*)d_in[6];
    const float* bhh   = (const float*)d_in[7];
    const float* e0    = (const float*)d_in[8];
    float* out = (float*)d_out;

    const size_t need = (size_t)ROWS * (G3 + NE) * sizeof(float);  // ~26.3 MB
    float* wbuf;
    if (ws_size >= need) {
        wbuf = (float*)d_ws;
    } else {
        wbuf = out + OUT1OFF;   // stash in out1; overwritten by copy at the end
    }
    float* Pbuf = wbuf + (size_t)ROWS * NE;

    proj_kernel<<<ROWS / PRJ_ROWS, 256, 0, stream>>>(h_seq, ek, Wi, bi, Wih, Pbuf, wbuf);
    scan_kernel<<<B_ * NE, 64, 0, stream>>>(Pbuf, wbuf, Whh, bih, bhh, e0, out);
    copy_kernel<<<2048, 256, 0, stream>>>((const float4*)out, (float4*)(out + OUT1OFF),
                                          OUT1OFF / 4);
}